// Round 8
// baseline (123.013 us; speedup 1.0000x reference)
//
#include <hip/hip_runtime.h>

// KMeans soft-assignment via bf16 hi/lo split MFMA (3 passes), fused softmax.
// logits = (2*x.c - ||c||^2)/T, T=0.1; ||x||^2 cancels in softmax.
// R18: TRUE 8-phase port (T3+T4+T5) + fused direct-store epilogue.
// R17 (counted vmcnt on monolithic loop) was +2% -- consistent with guide:
// T4 is null without the per-phase {ds-read || stage-issue || MFMA}
// interleave, and T5 is null without phase role-split (m196/m190/m218b).
// Arithmetic: per chunk/CU MFMA 3725cyc, LDS-read 3072cyc, VALU 640cyc;
// measured K-phase ~31us == their SERIAL SUM; overlap floor ~13us.
// Per chunk: convert A(ks) -> issue A(ks+1) -> counted vmcnt(4) ->
// s_barrier (DMA(ks) resident, A(ks+1) in flight) -> 4 sub-phases, each:
// {8 ds_read (4 tiles x bh/bl) + 2 DMA issues for ks+1} -> s_barrier ->
// lgkmcnt(0)+sched_barrier (rule 18) -> setprio(1) 24 MFMA setprio(0) ->
// s_barrier. Sub-phase barriers are schedule-only (buffer safety still
// guarded by the counted chunk barrier) -- cannot corrupt, only slow.
// Epilogue: direct scalar stores (16-lane 64B segments, line-merged in
// L2), no lbuf transpose, no post-stats barriers; stores drain at endpgm.
// Math identical per element -> absmax unchanged (0.00390625).
// x: [32768,256] f32, c: [512,256] f32, out: [32768,512] f32
#define NROWS 32768
#define KC 512
#define DDIM 256
#define BM 128
#define BK 32
#define KCH (DDIM / BK)        // 8 k-chunks
#define CHUNK_USH (KC * BK)    // 16384 ushorts = 32 KB per chunk table

typedef __attribute__((ext_vector_type(8))) short bf16x8;
typedef __attribute__((ext_vector_type(4))) float f32x4;

union U8 { unsigned short u[8]; bf16x8 v; };

__device__ __forceinline__ unsigned short f2bf(float f) {   // RNE f32->bf16
    union { float f; unsigned int u; } a; a.f = f;
    unsigned int r = a.u + 0x7fffu + ((a.u >> 16) & 1u);
    return (unsigned short)(r >> 16);
}
__device__ __forceinline__ float bf2f(unsigned short h) {
    union { unsigned int u; float f; } a; a.u = ((unsigned int)h) << 16;
    return a.f;
}
// async global->LDS, 16B/lane; LDS dst must be wave-uniform base + lane*16
__device__ __forceinline__ void ld16(const void* g, void* l) {
    __builtin_amdgcn_global_load_lds(
        (const __attribute__((address_space(1))) unsigned int*)g,
        (__attribute__((address_space(3))) unsigned int*)l, 16, 0, 0);
}

// ---- prep: c -> chunk-major, LDS-swizzle-baked bf16 hi/lo + csq10 ----
// octet (col n, quad q) at chunk offset (n*4 + (q ^ ((n>>1)&3)))*8 ushorts
__global__ __launch_bounds__(64) void prep_c(const float* __restrict__ c,
                                             unsigned short* __restrict__ bhi,
                                             unsigned short* __restrict__ blo,
                                             float* __restrict__ csq10) {
    const int n = blockIdx.x, lane = threadIdx.x;
    const int d0 = lane * 4;
    float4 v = ((const float4*)(c + (size_t)n * DDIM))[lane];
    float vv[4] = {v.x, v.y, v.z, v.w};
    unsigned short hh[4], ll[4];
    float ssq = 0.f;
    #pragma unroll
    for (int i = 0; i < 4; ++i) {
        ssq += vv[i] * vv[i];
        hh[i] = f2bf(vv[i]);
        ll[i] = f2bf(vv[i] - bf2f(hh[i]));
    }
    #pragma unroll
    for (int off = 32; off; off >>= 1) ssq += __shfl_xor(ssq, off);
    if (lane == 0) csq10[n] = 10.f * ssq;
    const int ks = d0 >> 5;
    const int q  = (d0 >> 3) & 3;
    const int s  = q ^ ((n >> 1) & 3);
    const size_t dst = (size_t)ks * CHUNK_USH + (n * 4 + s) * 8 + (d0 & 7);
    *(ushort4*)(bhi + dst) = make_ushort4(hh[0], hh[1], hh[2], hh[3]);
    *(ushort4*)(blo + dst) = make_ushort4(ll[0], ll[1], ll[2], ll[3]);
}

// ---- main: 256 blocks x 512 threads (8 waves = 4 M-groups x 2 N-halves) ----
struct SmemK { unsigned short Bh[2][CHUNK_USH], Bl[2][CHUNK_USH]; };  // 128 KB

__global__ __launch_bounds__(512, 2) void kmeans_mfma(
    const float* __restrict__ x, const unsigned short* __restrict__ bhi,
    const unsigned short* __restrict__ blo, const float* __restrict__ csq10,
    float* __restrict__ out) {
    __shared__ __align__(16) SmemK sm;
    __shared__ float red[2][2][BM];   // 2 KB

    const int tid  = threadIdx.x;
    const int w    = tid >> 6, lane = tid & 63;
    const int wm   = w >> 1, wn = w & 1;
    const int cc   = lane & 15, q = lane >> 4;
    const int row0 = blockIdx.x * BM;

    f32x4 acc[2][16];
    #pragma unroll
    for (int mt = 0; mt < 2; ++mt)
        #pragma unroll
        for (int t = 0; t < 16; ++t) acc[mt][t] = (f32x4){0.f, 0.f, 0.f, 0.f};

    // A: lane owns rows (row0 + wm*32 + mt*16 + cc), k-octet q*8 per chunk
    const float* xA0 = x + (size_t)(row0 + wm * 32 + cc) * DDIM + q * 8;
    const float* xA1 = xA0 + (size_t)16 * DDIM;
    // B fragment offset within staged chunk
    const int sF = q ^ ((cc >> 1) & 3);
    const int bF = (4 * cc + sF) * 8;       // + (wn*16+t)*512
    // DMA slots: wave w, j=0..3 -> 1 KB segment (w*4+j)*512 ushorts
    const int dmaOff = (w * 4) * 512;

    // ---- prologue: issue A(0), then DMA chunk 0 -> buf 0 (no barrier yet) ----
    float4 c00 = *(const float4*)xA0;
    float4 c01 = *(const float4*)(xA0 + 4);
    float4 c10 = *(const float4*)xA1;
    float4 c11 = *(const float4*)(xA1 + 4);
    #pragma unroll
    for (int j = 0; j < 4; ++j) {
        const int o = dmaOff + j * 512;
        ld16(bhi + o + lane * 8, &sm.Bh[0][o]);
        ld16(blo + o + lane * 8, &sm.Bl[0][o]);
    }

    #pragma unroll
    for (int ks = 0; ks < KCH; ++ks) {
        const int pp = ks & 1;
        // convert A(ks): compiler-counted vmcnt(8) (DMA(ks) ops younger)
        bf16x8 ah[2], al[2];
        {
            float v0[8] = {c00.x, c00.y, c00.z, c00.w, c01.x, c01.y, c01.z, c01.w};
            float v1[8] = {c10.x, c10.y, c10.z, c10.w, c11.x, c11.y, c11.z, c11.w};
            U8 H0, L0, H1, L1;
            #pragma unroll
            for (int e = 0; e < 8; ++e) {
                H0.u[e] = f2bf(v0[e]); L0.u[e] = f2bf(v0[e] - bf2f(H0.u[e]));
                H1.u[e] = f2bf(v1[e]); L1.u[e] = f2bf(v1[e] - bf2f(H1.u[e]));
            }
            ah[0] = H0.v; al[0] = L0.v; ah[1] = H1.v; al[1] = L1.v;
        }
        // issue A(ks+1) raw (youngest; stays in flight across the barrier)
        float4 n00, n01, n10, n11;
        if (ks < KCH - 1) {
            const int kn = (ks + 1) * BK;
            n00 = *(const float4*)(xA0 + kn);
            n01 = *(const float4*)(xA0 + kn + 4);
            n10 = *(const float4*)(xA1 + kn);
            n11 = *(const float4*)(xA1 + kn + 4);
        }
        __builtin_amdgcn_sched_barrier(0);
        // counted wait: DMA(ks) complete; A(ks+1) (4 youngest) stays in flight
        if (ks < KCH - 1) {
            asm volatile("s_waitcnt vmcnt(4)" ::: "memory");
        } else {
            asm volatile("s_waitcnt vmcnt(0)" ::: "memory");
        }
        __builtin_amdgcn_s_barrier();
        __builtin_amdgcn_sched_barrier(0);

        // ---- 4 sub-phases (m201 template): {8 ds_read || 2 DMA} ->
        // barrier -> lgkmcnt(0) -> setprio(1) 24 MFMA setprio(0) -> barrier
        #pragma unroll
        for (int ph = 0; ph < 4; ++ph) {
            bf16x8 bh[4], bl[4];
            #pragma unroll
            for (int tt = 0; tt < 4; ++tt) {
                const int bo = (wn * 16 + ph * 4 + tt) * 512 + bF;
                bh[tt] = *(const bf16x8*)&sm.Bh[pp][bo];
                bl[tt] = *(const bf16x8*)&sm.Bl[pp][bo];
            }
            if (ks < KCH - 1) {   // stage 2 of 8 DMA ops for chunk ks+1
                const size_t cb = (size_t)(ks + 1) * CHUNK_USH;
                const int o = dmaOff + ph * 512;
                ld16(bhi + cb + o + lane * 8, &sm.Bh[1 - pp][o]);
                ld16(blo + cb + o + lane * 8, &sm.Bl[1 - pp][o]);
            }
            __builtin_amdgcn_s_barrier();
            asm volatile("s_waitcnt lgkmcnt(0)" ::: "memory");
            __builtin_amdgcn_sched_barrier(0);
            __builtin_amdgcn_s_setprio(1);
            #pragma unroll
            for (int tt = 0; tt < 4; ++tt) {
                const int t = ph * 4 + tt;
                acc[0][t] = __builtin_amdgcn_mfma_f32_16x16x32_bf16(ah[0], bh[tt], acc[0][t], 0, 0, 0);
                acc[1][t] = __builtin_amdgcn_mfma_f32_16x16x32_bf16(ah[1], bh[tt], acc[1][t], 0, 0, 0);
                acc[0][t] = __builtin_amdgcn_mfma_f32_16x16x32_bf16(ah[0], bl[tt], acc[0][t], 0, 0, 0);
                acc[1][t] = __builtin_amdgcn_mfma_f32_16x16x32_bf16(ah[1], bl[tt], acc[1][t], 0, 0, 0);
                acc[0][t] = __builtin_amdgcn_mfma_f32_16x16x32_bf16(al[0], bh[tt], acc[0][t], 0, 0, 0);
                acc[1][t] = __builtin_amdgcn_mfma_f32_16x16x32_bf16(al[1], bh[tt], acc[1][t], 0, 0, 0);
            }
            __builtin_amdgcn_s_setprio(0);
            __builtin_amdgcn_sched_barrier(0);
            __builtin_amdgcn_s_barrier();
        }
        c00 = n00; c01 = n01; c10 = n10; c11 = n11;
    }

    // ---- softmax stats: reduce over t, then cc-lanes, then wn pair via LDS ----
    float csqv[16];
    #pragma unroll
    for (int t = 0; t < 16; ++t) csqv[t] = csq10[wn * 256 + t * 16 + cc];
    const int rb = wm * 32 + q * 4;   // + mt*16 + g
    float M[2][4], I[2][4];
    #pragma unroll
    for (int mt = 0; mt < 2; ++mt)
        #pragma unroll
        for (int g = 0; g < 4; ++g) {
            float pm = -1e30f;
            #pragma unroll
            for (int t = 0; t < 16; ++t) pm = fmaxf(pm, 20.f * acc[mt][t][g] - csqv[t]);
            #pragma unroll
            for (int off = 1; off < 16; off <<= 1) pm = fmaxf(pm, __shfl_xor(pm, off));
            if (cc == 0) red[0][wn][rb + mt * 16 + g] = pm;
            M[mt][g] = pm;
        }
    __syncthreads();
    #pragma unroll
    for (int mt = 0; mt < 2; ++mt)
        #pragma unroll
        for (int g = 0; g < 4; ++g) {
            M[mt][g] = fmaxf(M[mt][g], red[0][1 - wn][rb + mt * 16 + g]);
            float ps = 0.f;
            #pragma unroll
            for (int t = 0; t < 16; ++t) ps += __expf(20.f * acc[mt][t][g] - csqv[t] - M[mt][g]);
            #pragma unroll
            for (int off = 1; off < 16; off <<= 1) ps += __shfl_xor(ps, off);
            if (cc == 0) red[1][wn][rb + mt * 16 + g] = ps;
        }
    __syncthreads();
    #pragma unroll
    for (int mt = 0; mt < 2; ++mt)
        #pragma unroll
        for (int g = 0; g < 4; ++g)
            I[mt][g] = 1.f / (red[1][0][rb + mt * 16 + g] + red[1][1][rb + mt * 16 + g]);

    // ---- fused direct-store epilogue: no lbuf, no barriers; 64B-coalesced
    // segments (16 cc lanes), line-merged in L2; stores drain at endpgm ----
    #pragma unroll
    for (int mt = 0; mt < 2; ++mt)
        #pragma unroll
        for (int g = 0; g < 4; ++g) {
            const float mg = M[mt][g], ig = I[mt][g];
            float* orow = out + (size_t)(row0 + wm * 32 + mt * 16 + q * 4 + g) * KC
                              + wn * 256 + cc;
            #pragma unroll
            for (int t = 0; t < 16; ++t)
                orow[t * 16] = __expf(20.f * acc[mt][t][g] - csqv[t] - mg) * ig;
        }
}

extern "C" void kernel_launch(void* const* d_in, const int* in_sizes, int n_in,
                              void* d_out, int out_size, void* d_ws, size_t ws_size,
                              hipStream_t stream) {
    const float* x   = (const float*)d_in[0];
    const float* c   = (const float*)d_in[1];
    float*       out = (float*)d_out;

    unsigned short* bhi   = (unsigned short*)d_ws;                 // 256 KB
    unsigned short* blo   = bhi + (size_t)KCH * CHUNK_USH;         // 256 KB
    float*          csq10 = (float*)(blo + (size_t)KCH * CHUNK_USH);  // 2 KB

    prep_c<<<KC, 64, 0, stream>>>(c, bhi, blo, csq10);
    kmeans_mfma<<<NROWS / BM, 512, 0, stream>>>(x, bhi, blo, csq10, out);
}